// Round 4
// baseline (227.584 us; speedup 1.0000x reference)
//
#include <hip/hip_runtime.h>
#include <hip/hip_bf16.h>

typedef unsigned short ushort_t;

#define N_IMG 32
#define C_IN  128
#define C_OUT 256
#define H_SZ  56
#define W_SZ  56
#define HW_SZ (H_SZ * W_SZ)        // 3136
#define K_TOT (C_IN * 9)           // 1152
#define WP 64                      // padded width  (w' = w+1, zeros at 0,57..63)
#define HP 58                      // padded height (h1 = h+1, zeros at 0,57)
#define ROW_E (WP * C_IN)          // 8192 elements per padded (n,h1) slab

typedef __attribute__((ext_vector_type(8))) short bf16x8;
typedef __attribute__((ext_vector_type(4))) float floatx4;

__device__ __forceinline__ void gl_lds16(const ushort_t* g, ushort_t* l) {
  __builtin_amdgcn_global_load_lds(
      (const __attribute__((address_space(1))) void*)g,
      (__attribute__((address_space(3))) void*)l, 16, 0, 0);
}

__device__ __forceinline__ ushort_t f2bf(float f) {
  __hip_bfloat16 b = __float2bfloat16(f);
  return *reinterpret_cast<ushort_t*>(&b);
}

// w_q (int32 {-1,0,1}, [co][c][kh][kw]) -> w_t bf16 [co][tap*128+c]
__global__ void wtrans_kernel(const int* __restrict__ wq, ushort_t* __restrict__ wt) {
  int idx = blockIdx.x * 256 + threadIdx.x;
  if (idx >= C_OUT * K_TOT) return;
  int co = idx / K_TOT;
  int k  = idx - co * K_TOT;
  int tap = k >> 7;
  int c   = k & 127;
  int kh = tap / 3, kw = tap - kh * 3;
  int v = wq[((co * C_IN + c) * 3 + kh) * 3 + kw];
  wt[idx] = f2bf((float)v);
}

// x fp32 NCHW -> xp bf16 padded-NHWC: xp[n][h1][w'][c], h1=h+1 (0,57 zero),
// w'=w+1 (0,57..63 zero), +1 slack row at the end (OOB spill for discarded cols).
__global__ __launch_bounds__(256) void xpad_kernel(const float* __restrict__ x,
                                                   ushort_t* __restrict__ xp) {
  int b = blockIdx.x;                 // 0..N_IMG*HP (last = slack row)
  int t = threadIdx.x;
  ushort_t* row = xp + (size_t)b * ROW_E;
  int n = b / HP;
  int h1 = b - n * HP;
  if (b >= N_IMG * HP || h1 == 0 || h1 == HP - 1) {
    uint4 z = {0u, 0u, 0u, 0u};
    uint4* r4 = (uint4*)row;          // 16384 B = 1024 uint4
#pragma unroll
    for (int i = 0; i < 4; ++i) r4[i * 256 + t] = z;
    return;
  }
  __shared__ float tile[C_IN * 57];   // stride 57: store-phase 4-way max (free-ish)
  int h = h1 - 1;
  const float* xb = x + (size_t)n * C_IN * HW_SZ + h * W_SZ;
#pragma unroll
  for (int i = 0; i < 7; ++i) {
    int idx = i * 256 + t;            // 0..1791 = 128 c * 14 float4
    int c = idx / 14, f = idx - c * 14;
    float4 v = *(const float4*)(xb + (size_t)c * HW_SZ + f * 4);
    float* dst = &tile[c * 57 + f * 4];
    dst[0] = v.x; dst[1] = v.y; dst[2] = v.z; dst[3] = v.w;
  }
  __syncthreads();
  unsigned int* r32 = (unsigned int*)row;
#pragma unroll
  for (int i = 0; i < 16; ++i) {
    int idx = i * 256 + t;            // 0..4095 = 64 w' * 64 cpair
    int wp = idx >> 6, cp = idx & 63;
    unsigned int u = 0;
    if (wp >= 1 && wp <= W_SZ) {
      int w = wp - 1;
      u = (unsigned int)f2bf(tile[(2 * cp) * 57 + w]) |
          ((unsigned int)f2bf(tile[(2 * cp + 1) * 57 + w]) << 16);
    }
    r32[wp * 64 + cp] = u;            // 256 B contiguous per w'
  }
}

// Implicit GEMM, 256x256 tile, 8 waves (512 thr), BK=64, m201-style 4-phase
// schedule per K-tile. K = 9 taps x 2 halves = 18 K-tiles; dbuf parity =
// k-half (compile-time). Per K-tile (buf b, next tile -> buf b^1):
//  ph0: stage next-A (4 gl_lds) ; vmcnt(4) [my 8 for THIS tile landed,
//       4 new stay in flight] ; barrier [=> buffer valid for ALL waves] ;
//       ds_read A-m0(8)+B-n0(4) ; lgkmcnt(0) ; setprio 16 MFMA ; barrier
//  ph1: ds_read B-n1(4) ; stage next-B (4 gl_lds) ; barrier ; 16 MFMA ; barrier
//  ph2: ds_read A-m1(8) ; barrier ; 16 MFMA (reuse B-n1) ; barrier
//  ph3: ds_read B-n0(4) ; barrier ; 16 MFMA ; barrier
// vmcnt never drains to 0 in steady state (T4); stage writes go to buf^1,
// whose last readers retired before the previous tile's end barrier.
// LDS swizzle: slot = chunk ^ (row&7), staged via pre-swizzled GLOBAL
// source (linear gl_lds dest) — measured 0 bank conflicts in round 2/3.
__global__ __launch_bounds__(512, 2) void bitconv_kernel(
    const ushort_t* __restrict__ wt, const ushort_t* __restrict__ xp,
    const float* __restrict__ s, const float* __restrict__ bias,
    float* __restrict__ out) {
  __shared__ ushort_t As[2 * 16384];   // 2 bufs x 256 co x 64 k (64 KB)
  __shared__ ushort_t Bs[2 * 16384];   // 2 bufs x 256 sp x 64 k (64 KB)

  int d = blockIdx.x;                  // 448 = 8 XCD * 56
  int sp_tile = (d & 7) * 56 + (d >> 3);   // contiguous 56 tiles per XCD

  int tid  = threadIdx.x;
  int lane = tid & 63;
  int wid  = tid >> 6;                 // 0..7
  int l15  = lane & 15;
  int quad = lane >> 4;
  int wave_m = (wid >> 2) * 128;       // 2 M-groups
  int wave_n = (wid & 3) * 64;         // 4 N-groups

  // ---- staging addressing: thread t covers row (t>>3) of each 64-row sweep,
  // fetched global chunk q = (lane&7)^(lane>>3) so the LINEAR gl_lds dest
  // (base + lane*16B) lands at slot = chunk ^ (row&7).
  int qoff = ((lane & 7) ^ (lane >> 3)) * 8;
  const ushort_t* a_base = wt + (size_t)(tid >> 3) * K_TOT + qoff;
  const ushort_t* b_base[2][2];
#pragma unroll
  for (int h = 0; h < 2; ++h)
#pragma unroll
    for (int s2 = 0; s2 < 2; ++s2) {
      int nh = sp_tile * 4 + h * 2 + s2;         // padded row index 0..1791
      int n  = nh / H_SZ, hi = nh - n * H_SZ;
      b_base[h][s2] =
          xp + (size_t)((n * HP + 1 + hi) * WP + (tid >> 3) + 1) * C_IN + qoff;
    }
  // wave-uniform LDS dest element offsets per (h,s2)
  int sd00 = (0 * 128 + 0 * 64 + wid * 8) * 64;
  int sd01 = (0 * 128 + 1 * 64 + wid * 8) * 64;
  int sd10 = (1 * 128 + 0 * 64 + wid * 8) * 64;
  int sd11 = (1 * 128 + 1 * 64 + wid * 8) * 64;

  // ---- fragment-read addressing: row = group + l15, chunk c = quad + 4ks,
  // slot = c ^ (l15&7)  ->  ks flips ^32 elements.
  int ko0 = (quad ^ (l15 & 7)) * 8;
  int ko1 = ko0 ^ 32;
  int ar = (wave_m + l15) * 64;
  int br = (wave_n + l15) * 64;

  floatx4 acc[8][4];
#pragma unroll
  for (int mi = 0; mi < 8; ++mi)
#pragma unroll
    for (int ni = 0; ni < 4; ++ni)
      acc[mi][ni] = (floatx4){0.f, 0.f, 0.f, 0.f};

  auto stageA = [&](int NB, int s_aoff) {
    gl_lds16(a_base + 0 * K_TOT + s_aoff,                 &As[NB + sd00]);
    gl_lds16(a_base + 64 * K_TOT + s_aoff,                &As[NB + sd01]);
    gl_lds16(a_base + 128 * K_TOT + s_aoff,               &As[NB + sd10]);
    gl_lds16(a_base + 192 * K_TOT + s_aoff,               &As[NB + sd11]);
  };
  auto stageB = [&](int NB, int s_boff) {
    gl_lds16(b_base[0][0] + s_boff, &Bs[NB + sd00]);
    gl_lds16(b_base[0][1] + s_boff, &Bs[NB + sd01]);
    gl_lds16(b_base[1][0] + s_boff, &Bs[NB + sd10]);
    gl_lds16(b_base[1][1] + s_boff, &Bs[NB + sd11]);
  };

  auto tile = [&](int AB, int NB, int s_aoff, int s_boff, bool do_stage) {
    bf16x8 af[4][2], bn0[2][2], bn1[2][2];
    // ---------------- ph0: quadrant (m0, n0)
    if (do_stage) {
      stageA(NB, s_aoff);
      asm volatile("s_waitcnt vmcnt(4)" ::: "memory");
    } else {
      asm volatile("s_waitcnt vmcnt(0)" ::: "memory");
    }
    __builtin_amdgcn_s_barrier();      // buffer AB now valid for all waves
    asm volatile("" ::: "memory");
#pragma unroll
    for (int mi = 0; mi < 4; ++mi) {
      af[mi][0] = *(const bf16x8*)&As[AB + ar + mi * 1024 + ko0];
      af[mi][1] = *(const bf16x8*)&As[AB + ar + mi * 1024 + ko1];
    }
#pragma unroll
    for (int ni = 0; ni < 2; ++ni) {
      bn0[ni][0] = *(const bf16x8*)&Bs[AB + br + ni * 1024 + ko0];
      bn0[ni][1] = *(const bf16x8*)&Bs[AB + br + ni * 1024 + ko1];
    }
    asm volatile("s_waitcnt lgkmcnt(0)" ::: "memory");
    __builtin_amdgcn_sched_barrier(0);
    __builtin_amdgcn_s_setprio(1);
#pragma unroll
    for (int mi = 0; mi < 4; ++mi)
#pragma unroll
      for (int ni = 0; ni < 2; ++ni)
#pragma unroll
        for (int ks = 0; ks < 2; ++ks)
          acc[mi][ni] = __builtin_amdgcn_mfma_f32_16x16x32_bf16(
              af[mi][ks], bn0[ni][ks], acc[mi][ni], 0, 0, 0);
    __builtin_amdgcn_s_setprio(0);
    asm volatile("" ::: "memory");
    __builtin_amdgcn_s_barrier();
    asm volatile("" ::: "memory");
    // ---------------- ph1: quadrant (m0, n1)
#pragma unroll
    for (int ni = 0; ni < 2; ++ni) {
      bn1[ni][0] = *(const bf16x8*)&Bs[AB + br + (2 + ni) * 1024 + ko0];
      bn1[ni][1] = *(const bf16x8*)&Bs[AB + br + (2 + ni) * 1024 + ko1];
    }
    if (do_stage) stageB(NB, s_boff);
    asm volatile("" ::: "memory");
    __builtin_amdgcn_s_barrier();
    asm volatile("s_waitcnt lgkmcnt(0)" ::: "memory");
    __builtin_amdgcn_sched_barrier(0);
    __builtin_amdgcn_s_setprio(1);
#pragma unroll
    for (int mi = 0; mi < 4; ++mi)
#pragma unroll
      for (int ni = 0; ni < 2; ++ni)
#pragma unroll
        for (int ks = 0; ks < 2; ++ks)
          acc[mi][2 + ni] = __builtin_amdgcn_mfma_f32_16x16x32_bf16(
              af[mi][ks], bn1[ni][ks], acc[mi][2 + ni], 0, 0, 0);
    __builtin_amdgcn_s_setprio(0);
    asm volatile("" ::: "memory");
    __builtin_amdgcn_s_barrier();
    asm volatile("" ::: "memory");
    // ---------------- ph2: quadrant (m1, n1)
#pragma unroll
    for (int mi = 0; mi < 4; ++mi) {
      af[mi][0] = *(const bf16x8*)&As[AB + ar + (4 + mi) * 1024 + ko0];
      af[mi][1] = *(const bf16x8*)&As[AB + ar + (4 + mi) * 1024 + ko1];
    }
    asm volatile("" ::: "memory");
    __builtin_amdgcn_s_barrier();
    asm volatile("s_waitcnt lgkmcnt(0)" ::: "memory");
    __builtin_amdgcn_sched_barrier(0);
    __builtin_amdgcn_s_setprio(1);
#pragma unroll
    for (int mi = 0; mi < 4; ++mi)
#pragma unroll
      for (int ni = 0; ni < 2; ++ni)
#pragma unroll
        for (int ks = 0; ks < 2; ++ks)
          acc[4 + mi][2 + ni] = __builtin_amdgcn_mfma_f32_16x16x32_bf16(
              af[mi][ks], bn1[ni][ks], acc[4 + mi][2 + ni], 0, 0, 0);
    __builtin_amdgcn_s_setprio(0);
    asm volatile("" ::: "memory");
    __builtin_amdgcn_s_barrier();
    asm volatile("" ::: "memory");
    // ---------------- ph3: quadrant (m1, n0)
#pragma unroll
    for (int ni = 0; ni < 2; ++ni) {
      bn0[ni][0] = *(const bf16x8*)&Bs[AB + br + ni * 1024 + ko0];
      bn0[ni][1] = *(const bf16x8*)&Bs[AB + br + ni * 1024 + ko1];
    }
    asm volatile("" ::: "memory");
    __builtin_amdgcn_s_barrier();
    asm volatile("s_waitcnt lgkmcnt(0)" ::: "memory");
    __builtin_amdgcn_sched_barrier(0);
    __builtin_amdgcn_s_setprio(1);
#pragma unroll
    for (int mi = 0; mi < 4; ++mi)
#pragma unroll
      for (int ni = 0; ni < 2; ++ni)
#pragma unroll
        for (int ks = 0; ks < 2; ++ks)
          acc[4 + mi][ni] = __builtin_amdgcn_mfma_f32_16x16x32_bf16(
              af[mi][ks], bn0[ni][ks], acc[4 + mi][ni], 0, 0, 0);
    __builtin_amdgcn_s_setprio(0);
    asm volatile("" ::: "memory");
    __builtin_amdgcn_s_barrier();
    asm volatile("" ::: "memory");
  };

  // prologue: stage K-tile 0 (tap (-1,-1), half 0) into buf0
  stageA(0, 0);
  stageB(0, -ROW_E - C_IN);

#pragma unroll 1
  for (int kh = -1; kh <= 1; ++kh) {
#pragma unroll 1
    for (int kw = -1; kw <= 1; ++kw) {
      int tapidx = (kh + 1) * 3 + (kw + 1);
      bool last = (kh == 1) && (kw == 1);
      int nkh = (kw == 1) ? kh + 1 : kh;
      int nkw = (kw == 1) ? -1 : kw + 1;
      // half 0 in buf0; stages (kh,kw, half1) -> buf1
      tile(0, 16384, tapidx * 128 + 64, kh * ROW_E + kw * C_IN + 64, true);
      // half 1 in buf1; stages (nkh,nkw, half0) -> buf0
      tile(16384, 0, (tapidx + 1) * 128, nkh * ROW_E + nkw * C_IN, !last);
    }
  }

  // Epilogue: per wave 128 co x 64 sp. col(sp)=l15, row(co)=quad*4+rg.
  int nh_w = sp_tile * 4 + (wid & 3);
  int n_out = nh_w / H_SZ, h_img = nh_w - n_out * H_SZ;
  float* obase = out + (size_t)n_out * C_OUT * HW_SZ + h_img * W_SZ;
#pragma unroll
  for (int mi = 0; mi < 8; ++mi) {
#pragma unroll
    for (int rg = 0; rg < 4; ++rg) {
      int co = wave_m + mi * 16 + quad * 4 + rg;
      float sv = s[co];
      float bv = bias[co];
      float* ob = obase + (size_t)co * HW_SZ;
#pragma unroll
      for (int ni = 0; ni < 4; ++ni) {
        int w2 = ni * 16 + l15;       // 0..63 padded col
        if (w2 < W_SZ)
          ob[w2] = acc[mi][ni][rg] * sv + bv;
      }
    }
  }
}

extern "C" void kernel_launch(void* const* d_in, const int* in_sizes, int n_in,
                              void* d_out, int out_size, void* d_ws, size_t ws_size,
                              hipStream_t stream) {
  const float* x    = (const float*)d_in[0];
  const int*   wq   = (const int*)d_in[1];
  const float* s    = (const float*)d_in[2];
  const float* bias = (const float*)d_in[3];
  float* out = (float*)d_out;

  char* ws = (char*)d_ws;
  ushort_t* wt = (ushort_t*)ws;                          // 589,824 B
  ushort_t* xp = (ushort_t*)(ws + 589824);               // (32*58+1)*16384 B ≈ 30.4 MB

  hipLaunchKernelGGL(wtrans_kernel, dim3((C_OUT * K_TOT) / 256), dim3(256), 0, stream,
                     wq, wt);
  hipLaunchKernelGGL(xpad_kernel, dim3(N_IMG * HP + 1), dim3(256), 0, stream, x, xp);
  hipLaunchKernelGGL(bitconv_kernel, dim3(448), dim3(512), 0, stream,
                     wt, xp, s, bias, out);
}

// Round 5
// 215.449 us; speedup vs baseline: 1.0563x; 1.0563x over previous
//
#include <hip/hip_runtime.h>
#include <hip/hip_bf16.h>

typedef unsigned short ushort_t;

#define N_IMG 32
#define C_IN  128
#define C_OUT 256
#define H_SZ  56
#define W_SZ  56
#define HW_SZ (H_SZ * W_SZ)        // 3136
#define K_TOT (C_IN * 9)           // 1152
#define WP 64                      // padded width  (w' = w+1, zeros at 0,57..63)
#define HP 58                      // padded height (h1 = h+1, zeros at 0,57)
#define ROW_E (WP * C_IN)          // 8192 elements per padded (n,h1) slab

typedef __attribute__((ext_vector_type(8))) short bf16x8;
typedef __attribute__((ext_vector_type(4))) float floatx4;

__device__ __forceinline__ void gl_lds16(const ushort_t* g, ushort_t* l) {
  __builtin_amdgcn_global_load_lds(
      (const __attribute__((address_space(1))) void*)g,
      (__attribute__((address_space(3))) void*)l, 16, 0, 0);
}

__device__ __forceinline__ ushort_t f2bf(float f) {
  __hip_bfloat16 b = __float2bfloat16(f);
  return *reinterpret_cast<ushort_t*>(&b);
}

// w_q (int32 {-1,0,1}, [co][c][kh][kw]) -> w_t bf16 [co][tap*128+c]
__global__ void wtrans_kernel(const int* __restrict__ wq, ushort_t* __restrict__ wt) {
  int idx = blockIdx.x * 256 + threadIdx.x;
  if (idx >= C_OUT * K_TOT) return;
  int co = idx / K_TOT;
  int k  = idx - co * K_TOT;
  int tap = k >> 7;
  int c   = k & 127;
  int kh = tap / 3, kw = tap - kh * 3;
  int v = wq[((co * C_IN + c) * 3 + kh) * 3 + kw];
  wt[idx] = f2bf((float)v);
}

// x fp32 NCHW -> xp bf16 padded-NHWC: xp[n][h1][w'][c], h1=h+1 (0,57 zero),
// w'=w+1 (0,57..63 zero), +1 slack row at the end (OOB spill for discarded cols).
__global__ __launch_bounds__(256) void xpad_kernel(const float* __restrict__ x,
                                                   ushort_t* __restrict__ xp) {
  int b = blockIdx.x;                 // 0..N_IMG*HP (last = slack row)
  int t = threadIdx.x;
  ushort_t* row = xp + (size_t)b * ROW_E;
  int n = b / HP;
  int h1 = b - n * HP;
  if (b >= N_IMG * HP || h1 == 0 || h1 == HP - 1) {
    uint4 z = {0u, 0u, 0u, 0u};
    uint4* r4 = (uint4*)row;          // 16384 B = 1024 uint4
#pragma unroll
    for (int i = 0; i < 4; ++i) r4[i * 256 + t] = z;
    return;
  }
  __shared__ float tile[C_IN * 57];   // stride 57: store-phase 4-way max (free-ish)
  int h = h1 - 1;
  const float* xb = x + (size_t)n * C_IN * HW_SZ + h * W_SZ;
#pragma unroll
  for (int i = 0; i < 7; ++i) {
    int idx = i * 256 + t;            // 0..1791 = 128 c * 14 float4
    int c = idx / 14, f = idx - c * 14;
    float4 v = *(const float4*)(xb + (size_t)c * HW_SZ + f * 4);
    float* dst = &tile[c * 57 + f * 4];
    dst[0] = v.x; dst[1] = v.y; dst[2] = v.z; dst[3] = v.w;
  }
  __syncthreads();
  unsigned int* r32 = (unsigned int*)row;
#pragma unroll
  for (int i = 0; i < 16; ++i) {
    int idx = i * 256 + t;            // 0..4095 = 64 w' * 64 cpair
    int wp = idx >> 6, cp = idx & 63;
    unsigned int u = 0;
    if (wp >= 1 && wp <= W_SZ) {
      int w = wp - 1;
      u = (unsigned int)f2bf(tile[(2 * cp) * 57 + w]) |
          ((unsigned int)f2bf(tile[(2 * cp + 1) * 57 + w]) << 16);
    }
    r32[wp * 64 + cp] = u;            // 256 B contiguous per w'
  }
}

// Implicit GEMM, 256x256 tile, 8 waves (512 thr), BK=64, R2-style FLAT
// double-buffered schedule: 18 fully-unrolled K-tiles, per tile:
//   stage(next tile, 8 gl_lds) ; s_waitcnt vmcnt(8) [this tile's 8 landed,
//   next 8 stay in flight] ; s_barrier ; 24 ds_read_b128 + 64 MFMA
//   (compiler-scheduled, no pins) ; s_barrier.
// Rationale (R4 post-mortem): per-SIMD MFMA work per K-tile = 2 waves x 64
// MFMA x ~19.4cy = ~2.5K cy; one barrier-pair (~1-2K cy convoy) per K-tile
// amortizes 4x better than R4's 8-barrier 4-phase, and 4x better than R2's
// 128x128 tile (620 cy/step). vmcnt never drains to 0 in the main loop.
// LDS swizzle: slot = chunk ^ (row&7) via pre-swizzled GLOBAL source with
// linear gl_lds dest (measured 0 bank conflicts, rounds 2-4).
__global__ __launch_bounds__(512, 2) void bitconv_kernel(
    const ushort_t* __restrict__ wt, const ushort_t* __restrict__ xp,
    const float* __restrict__ s, const float* __restrict__ bias,
    float* __restrict__ out) {
  __shared__ ushort_t As[2 * 16384];   // 2 bufs x 256 co x 64 k (64 KB)
  __shared__ ushort_t Bs[2 * 16384];   // 2 bufs x 256 sp x 64 k (64 KB)

  int d = blockIdx.x;                  // 448 = 8 XCD * 56
  int sp_tile = (d & 7) * 56 + (d >> 3);   // contiguous 56 tiles per XCD

  int tid  = threadIdx.x;
  int lane = tid & 63;
  int wid  = tid >> 6;                 // 0..7
  int l15  = lane & 15;
  int quad = lane >> 4;
  int wave_m = (wid >> 2) * 128;       // 2 M-groups
  int wave_n = (wid & 3) * 64;         // 4 N-groups

  // ---- staging addressing: thread t covers row (t>>3) of each 64-row sweep,
  // fetched global chunk q = (lane&7)^(lane>>3) so the LINEAR gl_lds dest
  // (base + lane*16B) lands at slot = chunk ^ (row&7).
  int qoff = ((lane & 7) ^ (lane >> 3)) * 8;
  const ushort_t* a_base = wt + (size_t)(tid >> 3) * K_TOT + qoff;
  const ushort_t* b_base[2][2];
#pragma unroll
  for (int h = 0; h < 2; ++h)
#pragma unroll
    for (int s2 = 0; s2 < 2; ++s2) {
      int nh = sp_tile * 4 + h * 2 + s2;         // padded row index 0..1791
      int n  = nh / H_SZ, hi = nh - n * H_SZ;
      b_base[h][s2] =
          xp + (size_t)((n * HP + 1 + hi) * WP + (tid >> 3) + 1) * C_IN + qoff;
    }
  // wave-uniform LDS dest element offsets per 64-row segment
  int sd0 = (0 * 64 + wid * 8) * 64;
  int sd1 = (1 * 64 + wid * 8) * 64;
  int sd2 = (2 * 64 + wid * 8) * 64;
  int sd3 = (3 * 64 + wid * 8) * 64;

  // ---- fragment-read addressing: row = group + l15, chunk c = quad + 4ks,
  // slot = c ^ (l15&7)  ->  ks flips ^32 elements.
  int ko0 = (quad ^ (l15 & 7)) * 8;
  int ko1 = ko0 ^ 32;
  int ar = (wave_m + l15) * 64;
  int br = (wave_n + l15) * 64;

  floatx4 acc[8][4];
#pragma unroll
  for (int mi = 0; mi < 8; ++mi)
#pragma unroll
    for (int ni = 0; ni < 4; ++ni)
      acc[mi][ni] = (floatx4){0.f, 0.f, 0.f, 0.f};

  auto stageA = [&](int NB, int s_aoff) {
    gl_lds16(a_base + 0 * K_TOT + s_aoff,   &As[NB + sd0]);
    gl_lds16(a_base + 64 * K_TOT + s_aoff,  &As[NB + sd1]);
    gl_lds16(a_base + 128 * K_TOT + s_aoff, &As[NB + sd2]);
    gl_lds16(a_base + 192 * K_TOT + s_aoff, &As[NB + sd3]);
  };
  auto stageB = [&](int NB, int s_boff) {
    gl_lds16(b_base[0][0] + s_boff, &Bs[NB + sd0]);
    gl_lds16(b_base[0][1] + s_boff, &Bs[NB + sd1]);
    gl_lds16(b_base[1][0] + s_boff, &Bs[NB + sd2]);
    gl_lds16(b_base[1][1] + s_boff, &Bs[NB + sd3]);
  };

  // prologue: stage K-tile 0 (tap (-1,-1), half 0) into buf0
  stageA(0, 0);
  stageB(0, -ROW_E - C_IN);

#pragma unroll
  for (int kt = 0; kt < 18; ++kt) {
    int cb = (kt & 1) * 16384;         // current buffer (element offset)
    int nb = 16384 - cb;               // next buffer
    if (kt < 17) {
      int ntap  = (kt + 1) >> 1;
      int nhalf = (kt + 1) & 1;
      stageA(nb, ntap * C_IN + nhalf * 64);
      stageB(nb, (ntap / 3 - 1) * ROW_E + (ntap % 3 - 1) * C_IN + nhalf * 64);
      asm volatile("s_waitcnt vmcnt(8)" ::: "memory");  // this tile's 8 landed
    } else {
      asm volatile("s_waitcnt vmcnt(0)" ::: "memory");
    }
    __builtin_amdgcn_s_barrier();      // buffer cb valid for all waves
    asm volatile("" ::: "memory");

    bf16x8 bfv[4][2], af[4][2];
#pragma unroll
    for (int ni = 0; ni < 4; ++ni) {
      bfv[ni][0] = *(const bf16x8*)&Bs[cb + br + ni * 1024 + ko0];
      bfv[ni][1] = *(const bf16x8*)&Bs[cb + br + ni * 1024 + ko1];
    }
    // half 1: m-rows 0..63 of the wave's 128
#pragma unroll
    for (int mi = 0; mi < 4; ++mi) {
      af[mi][0] = *(const bf16x8*)&As[cb + ar + mi * 1024 + ko0];
      af[mi][1] = *(const bf16x8*)&As[cb + ar + mi * 1024 + ko1];
    }
#pragma unroll
    for (int mi = 0; mi < 4; ++mi)
#pragma unroll
      for (int ni = 0; ni < 4; ++ni)
#pragma unroll
        for (int ks = 0; ks < 2; ++ks)
          acc[mi][ni] = __builtin_amdgcn_mfma_f32_16x16x32_bf16(
              af[mi][ks], bfv[ni][ks], acc[mi][ni], 0, 0, 0);
    // half 2: m-rows 64..127 (reuse bfv)
#pragma unroll
    for (int mi = 0; mi < 4; ++mi) {
      af[mi][0] = *(const bf16x8*)&As[cb + ar + (4 + mi) * 1024 + ko0];
      af[mi][1] = *(const bf16x8*)&As[cb + ar + (4 + mi) * 1024 + ko1];
    }
#pragma unroll
    for (int mi = 0; mi < 4; ++mi)
#pragma unroll
      for (int ni = 0; ni < 4; ++ni)
#pragma unroll
        for (int ks = 0; ks < 2; ++ks)
          acc[4 + mi][ni] = __builtin_amdgcn_mfma_f32_16x16x32_bf16(
              af[mi][ks], bfv[ni][ks], acc[4 + mi][ni], 0, 0, 0);

    asm volatile("" ::: "memory");
    __builtin_amdgcn_s_barrier();      // all reads of cb done; nb stage may land
    asm volatile("" ::: "memory");
  }

  // Epilogue: per wave 128 co x 64 sp. col(sp)=l15, row(co)=quad*4+rg.
  int nh_w = sp_tile * 4 + (wid & 3);
  int n_out = nh_w / H_SZ, h_img = nh_w - n_out * H_SZ;
  float* obase = out + (size_t)n_out * C_OUT * HW_SZ + h_img * W_SZ;
#pragma unroll
  for (int mi = 0; mi < 8; ++mi) {
#pragma unroll
    for (int rg = 0; rg < 4; ++rg) {
      int co = wave_m + mi * 16 + quad * 4 + rg;
      float sv = s[co];
      float bv = bias[co];
      float* ob = obase + (size_t)co * HW_SZ;
#pragma unroll
      for (int ni = 0; ni < 4; ++ni) {
        int w2 = ni * 16 + l15;       // 0..63 padded col
        if (w2 < W_SZ)
          ob[w2] = acc[mi][ni][rg] * sv + bv;
      }
    }
  }
}

extern "C" void kernel_launch(void* const* d_in, const int* in_sizes, int n_in,
                              void* d_out, int out_size, void* d_ws, size_t ws_size,
                              hipStream_t stream) {
  const float* x    = (const float*)d_in[0];
  const int*   wq   = (const int*)d_in[1];
  const float* s    = (const float*)d_in[2];
  const float* bias = (const float*)d_in[3];
  float* out = (float*)d_out;

  char* ws = (char*)d_ws;
  ushort_t* wt = (ushort_t*)ws;                          // 589,824 B
  ushort_t* xp = (ushort_t*)(ws + 589824);               // (32*58+1)*16384 B ≈ 30.4 MB

  hipLaunchKernelGGL(wtrans_kernel, dim3((C_OUT * K_TOT) / 256), dim3(256), 0, stream,
                     wq, wt);
  hipLaunchKernelGGL(xpad_kernel, dim3(N_IMG * HP + 1), dim3(256), 0, stream, x, xp);
  hipLaunchKernelGGL(bitconv_kernel, dim3(448), dim3(512), 0, stream,
                     wt, xp, s, bias, out);
}

// Round 7
// 214.569 us; speedup vs baseline: 1.0607x; 1.0041x over previous
//
#include <hip/hip_runtime.h>
#include <hip/hip_bf16.h>

typedef unsigned short ushort_t;

#define N_IMG 32
#define C_IN  128
#define C_OUT 256
#define H_SZ  56
#define W_SZ  56
#define HW_SZ (H_SZ * W_SZ)        // 3136
#define K_TOT (C_IN * 9)           // 1152
#define WP 64                      // padded width  (w' = w+1, zeros at 0,57..63)
#define HP 58                      // padded height (h1 = h+1, zeros at 0,57)
#define ROW_E (WP * C_IN)          // 8192 elements per padded (n,h1) slab

typedef __attribute__((ext_vector_type(8))) short bf16x8;
typedef __attribute__((ext_vector_type(4))) float floatx4;

__device__ __forceinline__ void gl_lds16(const ushort_t* g, ushort_t* l) {
  __builtin_amdgcn_global_load_lds(
      (const __attribute__((address_space(1))) void*)g,
      (__attribute__((address_space(3))) void*)l, 16, 0, 0);
}

__device__ __forceinline__ ushort_t f2bf(float f) {
  __hip_bfloat16 b = __float2bfloat16(f);
  return *reinterpret_cast<ushort_t*>(&b);
}

// w_q (int32 {-1,0,1}, [co][c][kh][kw]) -> w_t bf16 [co][tap*128+c]
__global__ void wtrans_kernel(const int* __restrict__ wq, ushort_t* __restrict__ wt) {
  int idx = blockIdx.x * 256 + threadIdx.x;
  if (idx >= C_OUT * K_TOT) return;
  int co = idx / K_TOT;
  int k  = idx - co * K_TOT;
  int tap = k >> 7;
  int c   = k & 127;
  int kh = tap / 3, kw = tap - kh * 3;
  int v = wq[((co * C_IN + c) * 3 + kh) * 3 + kw];
  wt[idx] = f2bf((float)v);
}

// x fp32 NCHW -> xp bf16 padded-NHWC: xp[n][h1][w'][c], h1=h+1 (0,57 zero),
// w'=w+1 (0,57..63 zero), +1 slack row at the end (OOB spill for discarded cols).
__global__ __launch_bounds__(256) void xpad_kernel(const float* __restrict__ x,
                                                   ushort_t* __restrict__ xp) {
  int b = blockIdx.x;                 // 0..N_IMG*HP (last = slack row)
  int t = threadIdx.x;
  ushort_t* row = xp + (size_t)b * ROW_E;
  int n = b / HP;
  int h1 = b - n * HP;
  if (b >= N_IMG * HP || h1 == 0 || h1 == HP - 1) {
    uint4 z = {0u, 0u, 0u, 0u};
    uint4* r4 = (uint4*)row;          // 16384 B = 1024 uint4
#pragma unroll
    for (int i = 0; i < 4; ++i) r4[i * 256 + t] = z;
    return;
  }
  __shared__ float tile[C_IN * 57];   // stride 57: store-phase 4-way max (free-ish)
  int h = h1 - 1;
  const float* xb = x + (size_t)n * C_IN * HW_SZ + h * W_SZ;
#pragma unroll
  for (int i = 0; i < 7; ++i) {
    int idx = i * 256 + t;            // 0..1791 = 128 c * 14 float4
    int c = idx / 14, f = idx - c * 14;
    float4 v = *(const float4*)(xb + (size_t)c * HW_SZ + f * 4);
    float* dst = &tile[c * 57 + f * 4];
    dst[0] = v.x; dst[1] = v.y; dst[2] = v.z; dst[3] = v.w;
  }
  __syncthreads();
  unsigned int* r32 = (unsigned int*)row;
#pragma unroll
  for (int i = 0; i < 16; ++i) {
    int idx = i * 256 + t;            // 0..4095 = 64 w' * 64 cpair
    int wp = idx >> 6, cp = idx & 63;
    unsigned int u = 0;
    if (wp >= 1 && wp <= W_SZ) {
      int w = wp - 1;
      u = (unsigned int)f2bf(tile[(2 * cp) * 57 + w]) |
          ((unsigned int)f2bf(tile[(2 * cp + 1) * 57 + w]) << 16);
    }
    r32[wp * 64 + cp] = u;            // 256 B contiguous per w'
  }
}

// Implicit GEMM, 256x256 tile, 8 waves (512 thr), BK=64, ROTATED dbuf
// schedule with ONE barrier per K-tile (vs R5's two):
//   iter kt: stage(kt+1 -> nb, 8 gl_lds) ; 24 ds_read_b128 + 64 MFMA from cb
//            (compiler-scheduled lgkmcnt) ; s_waitcnt vmcnt(0) [stages had
//            the whole ~2.5K-cy MFMA phase to land -> near-free] ; s_barrier.
// Safety: cb was validated by the PREVIOUS iter's barrier; this iter's reads
// of cb complete (into regs) before its own barrier; cb's next writer is the
// stage issued in iter kt+1, which every wave issues only after this barrier.
// Benefits vs R5: 18 barriers not 36, ds_read issue overlaps stage issue,
// vmcnt wait is maximally distant from issue. Geometry/swizzle identical to
// R5 (slot = chunk ^ (row&7) via pre-swizzled GLOBAL source, 0 conflicts).
__global__ __launch_bounds__(512, 2) void bitconv_kernel(
    const ushort_t* __restrict__ wt, const ushort_t* __restrict__ xp,
    const float* __restrict__ s, const float* __restrict__ bias,
    float* __restrict__ out) {
  __shared__ ushort_t As[2 * 16384];   // 2 bufs x 256 co x 64 k (64 KB)
  __shared__ ushort_t Bs[2 * 16384];   // 2 bufs x 256 sp x 64 k (64 KB)

  int d = blockIdx.x;                  // 448 = 8 XCD * 56
  int sp_tile = (d & 7) * 56 + (d >> 3);   // contiguous 56 tiles per XCD

  int tid  = threadIdx.x;
  int lane = tid & 63;
  int wid  = tid >> 6;                 // 0..7
  int l15  = lane & 15;
  int quad = lane >> 4;
  int wave_m = (wid >> 2) * 128;       // 2 M-groups
  int wave_n = (wid & 3) * 64;         // 4 N-groups

  // ---- staging addressing: thread t covers row (t>>3) of each 64-row sweep,
  // fetched global chunk q = (lane&7)^(lane>>3) so the LINEAR gl_lds dest
  // (base + lane*16B) lands at slot = chunk ^ (row&7).
  int qoff = ((lane & 7) ^ (lane >> 3)) * 8;
  const ushort_t* a_base = wt + (size_t)(tid >> 3) * K_TOT + qoff;
  const ushort_t* b_base[2][2];
#pragma unroll
  for (int h = 0; h < 2; ++h)
#pragma unroll
    for (int s2 = 0; s2 < 2; ++s2) {
      int nh = sp_tile * 4 + h * 2 + s2;         // padded row index 0..1791
      int n  = nh / H_SZ, hi = nh - n * H_SZ;
      b_base[h][s2] =
          xp + (size_t)((n * HP + 1 + hi) * WP + (tid >> 3) + 1) * C_IN + qoff;
    }
  // wave-uniform LDS dest element offsets per 64-row segment
  int sd0 = (0 * 64 + wid * 8) * 64;
  int sd1 = (1 * 64 + wid * 8) * 64;
  int sd2 = (2 * 64 + wid * 8) * 64;
  int sd3 = (3 * 64 + wid * 8) * 64;

  // ---- fragment-read addressing: row = group + l15, chunk c = quad + 4ks,
  // slot = c ^ (l15&7)  ->  ks flips ^32 elements.
  int ko0 = (quad ^ (l15 & 7)) * 8;
  int ko1 = ko0 ^ 32;
  int ar = (wave_m + l15) * 64;
  int br = (wave_n + l15) * 64;

  floatx4 acc[8][4];
#pragma unroll
  for (int mi = 0; mi < 8; ++mi)
#pragma unroll
    for (int ni = 0; ni < 4; ++ni)
      acc[mi][ni] = (floatx4){0.f, 0.f, 0.f, 0.f};

  auto stageA = [&](int NB, int s_aoff) {
    gl_lds16(a_base + 0 * K_TOT + s_aoff,   &As[NB + sd0]);
    gl_lds16(a_base + 64 * K_TOT + s_aoff,  &As[NB + sd1]);
    gl_lds16(a_base + 128 * K_TOT + s_aoff, &As[NB + sd2]);
    gl_lds16(a_base + 192 * K_TOT + s_aoff, &As[NB + sd3]);
  };
  auto stageB = [&](int NB, int s_boff) {
    gl_lds16(b_base[0][0] + s_boff, &Bs[NB + sd0]);
    gl_lds16(b_base[0][1] + s_boff, &Bs[NB + sd1]);
    gl_lds16(b_base[1][0] + s_boff, &Bs[NB + sd2]);
    gl_lds16(b_base[1][1] + s_boff, &Bs[NB + sd3]);
  };

  // prologue: stage K-tile 0 (tap (-1,-1), half 0) into buf0, validate it.
  stageA(0, 0);
  stageB(0, -ROW_E - C_IN);
  asm volatile("s_waitcnt vmcnt(0)" ::: "memory");
  __builtin_amdgcn_s_barrier();
  asm volatile("" ::: "memory");

#pragma unroll
  for (int kt = 0; kt < 18; ++kt) {
    int cb = (kt & 1) * 16384;         // current buffer (element offset)
    int nb = 16384 - cb;               // next buffer
    if (kt < 17) {
      int ntap  = (kt + 1) >> 1;
      int nhalf = (kt + 1) & 1;
      stageA(nb, ntap * C_IN + nhalf * 64);
      stageB(nb, (ntap / 3 - 1) * ROW_E + (ntap % 3 - 1) * C_IN + nhalf * 64);
    }

    bf16x8 bfv[4][2], af[4][2];
#pragma unroll
    for (int ni = 0; ni < 4; ++ni) {
      bfv[ni][0] = *(const bf16x8*)&Bs[cb + br + ni * 1024 + ko0];
      bfv[ni][1] = *(const bf16x8*)&Bs[cb + br + ni * 1024 + ko1];
    }
    // half 1: m-rows 0..63 of the wave's 128
#pragma unroll
    for (int mi = 0; mi < 4; ++mi) {
      af[mi][0] = *(const bf16x8*)&As[cb + ar + mi * 1024 + ko0];
      af[mi][1] = *(const bf16x8*)&As[cb + ar + mi * 1024 + ko1];
    }
#pragma unroll
    for (int mi = 0; mi < 4; ++mi)
#pragma unroll
      for (int ni = 0; ni < 4; ++ni)
#pragma unroll
        for (int ks = 0; ks < 2; ++ks)
          acc[mi][ni] = __builtin_amdgcn_mfma_f32_16x16x32_bf16(
              af[mi][ks], bfv[ni][ks], acc[mi][ni], 0, 0, 0);
    // half 2: m-rows 64..127 (reuse bfv)
#pragma unroll
    for (int mi = 0; mi < 4; ++mi) {
      af[mi][0] = *(const bf16x8*)&As[cb + ar + (4 + mi) * 1024 + ko0];
      af[mi][1] = *(const bf16x8*)&As[cb + ar + (4 + mi) * 1024 + ko1];
    }
#pragma unroll
    for (int mi = 0; mi < 4; ++mi)
#pragma unroll
      for (int ni = 0; ni < 4; ++ni)
#pragma unroll
        for (int ks = 0; ks < 2; ++ks)
          acc[4 + mi][ni] = __builtin_amdgcn_mfma_f32_16x16x32_bf16(
              af[mi][ks], bfv[ni][ks], acc[4 + mi][ni], 0, 0, 0);

    if (kt < 17) {
      // next buffer's 8 loads had the whole MFMA phase to land: near-free.
      asm volatile("s_waitcnt vmcnt(0)" ::: "memory");
      __builtin_amdgcn_s_barrier();    // reads of cb done + nb valid
      asm volatile("" ::: "memory");
    }
  }

  // Epilogue: per wave 128 co x 64 sp. col(sp)=l15, row(co)=quad*4+rg.
  int nh_w = sp_tile * 4 + (wid & 3);
  int n_out = nh_w / H_SZ, h_img = nh_w - n_out * H_SZ;
  float* obase = out + (size_t)n_out * C_OUT * HW_SZ + h_img * W_SZ;
#pragma unroll
  for (int mi = 0; mi < 8; ++mi) {
#pragma unroll
    for (int rg = 0; rg < 4; ++rg) {
      int co = wave_m + mi * 16 + quad * 4 + rg;
      float sv = s[co];
      float bv = bias[co];
      float* ob = obase + (size_t)co * HW_SZ;
#pragma unroll
      for (int ni = 0; ni < 4; ++ni) {
        int w2 = ni * 16 + l15;       // 0..63 padded col
        if (w2 < W_SZ)
          ob[w2] = acc[mi][ni][rg] * sv + bv;
      }
    }
  }
}

extern "C" void kernel_launch(void* const* d_in, const int* in_sizes, int n_in,
                              void* d_out, int out_size, void* d_ws, size_t ws_size,
                              hipStream_t stream) {
  const float* x    = (const float*)d_in[0];
  const int*   wq   = (const int*)d_in[1];
  const float* s    = (const float*)d_in[2];
  const float* bias = (const float*)d_in[3];
  float* out = (float*)d_out;

  char* ws = (char*)d_ws;
  ushort_t* wt = (ushort_t*)ws;                          // 589,824 B
  ushort_t* xp = (ushort_t*)(ws + 589824);               // (32*58+1)*16384 B ≈ 30.4 MB

  hipLaunchKernelGGL(wtrans_kernel, dim3((C_OUT * K_TOT) / 256), dim3(256), 0, stream,
                     wq, wt);
  hipLaunchKernelGGL(xpad_kernel, dim3(N_IMG * HP + 1), dim3(256), 0, stream, x, xp);
  hipLaunchKernelGGL(bitconv_kernel, dim3(448), dim3(512), 0, stream,
                     wt, xp, s, bias, out);
}